// Round 2
// baseline (2531.815 us; speedup 1.0000x reference)
//
#include <hip/hip_runtime.h>

#define T_ 64

typedef __attribute__((ext_vector_type(4))) float f32x4;
typedef __attribute__((ext_vector_type(8))) short s16x8;

__device__ __forceinline__ unsigned short f2bf(float f) {
  unsigned u = __float_as_uint(f);
  u = (u + 0x7FFFu + ((u >> 16) & 1u)) >> 16;
  return (unsigned short)u;
}
__device__ __forceinline__ float bf2f(unsigned short h) {
  return __uint_as_float(((unsigned)h) << 16);
}
__device__ __forceinline__ float eluf(float x) { return x > 0.f ? x : __expf(x) - 1.f; }
__device__ __forceinline__ float sigmf(float x) { return 1.f / (1.f + __expf(-x)); }
__device__ __forceinline__ float tanh_(float x) {
  float xx = fminf(fmaxf(x, -30.f), 30.f);
  float e = __expf(-2.f * xx);
  return (1.f - e) / (1.f + e);
}
__device__ __forceinline__ float softpf(float x) {
  return x > 20.f ? x : __logf(1.f + __expf(x));
}

// ---- workspace layout (bytes) ----
// emb_pre (bf16) [T*B][200]            : 26,214,400
// pk      (bf16) MFMA-packed weights   :    892,928
// swz     (bf16) emb_gemm B (validated):    425,984
#define OFF_PK  26214400
#define OFF_SWZ 27107328

// Packed B layout (nt-major, kt inner): idx = ((nt*KT + kt)*64 + lane)*8 + j
// holds W[k][n] with n = nt*16 + (lane&15), k = kt*32 + (lane>>4)*8 + j; zero pad.
__device__ void pack_mat(int idx, int stride, const float* __restrict__ W,
                         int K, int N, int KT, int NT, unsigned short* __restrict__ dst) {
  int total = KT * NT * 512;
  for (int i = idx; i < total; i += stride) {
    int j = i & 7, l = (i >> 3) & 63, rem = i >> 9;
    int kt = rem % KT, nt = rem / KT;
    int n = nt * 16 + (l & 15), k = kt * 32 + (l >> 4) * 8 + j;
    float v = (k < K && n < N) ? W[(size_t)k * N + n] : 0.f;
    dst[i] = f2bf(v);
  }
}

__global__ void prep_weights(const float* __restrict__ w1, const float* __restrict__ wi,
                             const float* __restrict__ wh, const float* __restrict__ i2,
                             const float* __restrict__ i3, const float* __restrict__ obs1w,
                             const float* __restrict__ o2,
                             unsigned short* __restrict__ pk,
                             unsigned short* __restrict__ swz) {
  int idx = blockIdx.x * blockDim.x + threadIdx.x;
  int stride = gridDim.x * blockDim.x;
  pack_mat(idx, stride, w1,   40, 200, 2, 16, pk);            // img1_w
  pack_mat(idx, stride, wi,  200, 600, 7, 40, pk + 16384);    // gru_wi
  pack_mat(idx, stride, wh,  200, 600, 7, 40, pk + 159744);   // gru_wh
  pack_mat(idx, stride, i2,  200, 200, 7, 16, pk + 303104);   // img2_w
  pack_mat(idx, stride, obs1w, 200, 200, 7, 16, pk + 360448); // obs1_w rows 0..199 (deter part)
  pack_mat(idx, stride, i3,  200, 60, 7, 4, pk + 417792);     // img3_w
  pack_mat(idx, stride, o2,  200, 60, 7, 4, pk + 432128);     // obs2_w
  // swz for emb_gemm: obs1_w rows 200..1223 (embed part) — validated layout
  for (int i = idx; i < 212992; i += stride) {
    int j = i & 7, l = (i >> 3) & 63, rem = i >> 9;
    int nt = rem % 13, kc = rem / 13;
    int k = kc * 32 + ((l >> 4) * 8) + j;
    int n = nt * 16 + (l & 15);
    float v = (n < 200) ? obs1w[(size_t)(200 + k) * 200 + n] : 0.0f;
    swz[i] = f2bf(v);
  }
}

// --------------------------------------------------------------------------
// emb_pre[t*B+b][n] = bf16( embed[b,t,:] @ obs1_w[200:,:] + obs1_b[n] )
// (unchanged from validated round-1 kernel)
// --------------------------------------------------------------------------
__global__ __launch_bounds__(256) void emb_gemm(const float* __restrict__ embed,
                                                const float* __restrict__ obs1b,
                                                const unsigned short* __restrict__ swz,
                                                unsigned short* __restrict__ emb_pre) {
  __shared__ __align__(16) unsigned short lds_A[64][40];
  int tid = threadIdx.x;
  int lane = tid & 63, w = tid >> 6;
  int R0 = blockIdx.x * 64;
  int tt = R0 >> 10;
  int bb = R0 & 1023;

  f32x4 acc[13];
#pragma unroll
  for (int nt = 0; nt < 13; ++nt) acc[nt] = (f32x4){0.f, 0.f, 0.f, 0.f};

  int i_row = tid >> 2, cg = tid & 3;
  const float* arow = embed + ((size_t)(bb + i_row) * 64 + tt) * 1024 + cg * 8;

  for (int kc = 0; kc < 32; ++kc) {
    __syncthreads();
    {
      const float* p = arow + kc * 32;
      f32x4 a0 = *(const f32x4*)p;
      f32x4 a1 = *(const f32x4*)(p + 4);
      unsigned short* dst = &lds_A[i_row][cg * 8];
      dst[0] = f2bf(a0[0]); dst[1] = f2bf(a0[1]); dst[2] = f2bf(a0[2]); dst[3] = f2bf(a0[3]);
      dst[4] = f2bf(a1[0]); dst[5] = f2bf(a1[1]); dst[6] = f2bf(a1[2]); dst[7] = f2bf(a1[3]);
    }
    __syncthreads();
    s16x8 af = *(const s16x8*)&lds_A[w * 16 + (lane & 15)][(lane >> 4) * 8];
    const unsigned short* bp = swz + (size_t)kc * 6656 + (size_t)lane * 8;
#pragma unroll
    for (int nt = 0; nt < 13; ++nt) {
      s16x8 bfv = *(const s16x8*)(bp + nt * 512);
      acc[nt] = __builtin_amdgcn_mfma_f32_16x16x32_bf16(af, bfv, acc[nt], 0, 0, 0);
    }
  }
  int r0 = R0 + w * 16 + ((lane >> 4) << 2);
  int c0 = lane & 15;
#pragma unroll
  for (int nt = 0; nt < 13; ++nt) {
    int n = nt * 16 + c0;
    if (n < 200) {
      float bv = obs1b[n];
#pragma unroll
      for (int rr = 0; rr < 4; ++rr)
        emb_pre[(size_t)(r0 + rr) * 200 + n] = f2bf(acc[nt][rr] + bv);
    }
  }
}

// --------------------------------------------------------------------------
// MFMA scan: 64 blocks x 512 threads; each block owns 16 batch rows, M=16.
// --------------------------------------------------------------------------
__global__ __launch_bounds__(512, 1) void scan16(
    const float* __restrict__ action, const float* __restrict__ eps_post,
    const float* __restrict__ eps_prior, const float* __restrict__ img1_b,
    const float* __restrict__ gru_bi, const float* __restrict__ gru_bh,
    const float* __restrict__ img2_b, const float* __restrict__ img3_b,
    const float* __restrict__ obs2_b, const unsigned short* __restrict__ pk,
    const unsigned short* __restrict__ emb_pre, float* __restrict__ out) {

  __shared__ __align__(16) float s_gi[600][20];   // [col][row-padded], stride 80B
  __shared__ __align__(16) float s_gh[600][20];
  __shared__ __align__(16) float s_deter[200][16];
  __shared__ __align__(16) unsigned short xA[28][16][8];   // A-frag layout: [k/8][row][k%8]
  __shared__ __align__(16) unsigned short dA[28][16][8];
  __shared__ __align__(16) unsigned short y1A[28][16][8];
  __shared__ __align__(16) unsigned short o1A[28][16][8];
  __shared__ __align__(16) unsigned short sA[8][16][8];    // [stoch|act], K=64 padded
  __shared__ __align__(16) float s_y[60][20];
  __shared__ __align__(16) float s_o[60][20];

  const unsigned short* pw1 = pk;            // KT2 NT16
  const unsigned short* pwi = pk + 16384;    // KT7 NT40
  const unsigned short* pwh = pk + 159744;
  const unsigned short* pi2 = pk + 303104;   // KT7 NT16
  const unsigned short* po1 = pk + 360448;
  const unsigned short* pi3 = pk + 417792;   // KT7 NT4
  const unsigned short* po2 = pk + 432128;

  const int tid = threadIdx.x;
  const int lane = tid & 63;
  const int w = tid >> 6;
  const int arow = lane & 15;   // A-row / C-col fragment index
  const int kg = lane >> 4;     // 0..3
  const int b0 = blockIdx.x * 16;

  // ---- init: zero carries and A-pad chunks (B pads are zero, so pad*B = 0;
  //      zeros also avoid NaN propagation from poisoned LDS)
  for (int i = tid; i < 1024; i += 512) ((unsigned short*)sA)[i] = 0;
  for (int i = tid; i < 3584; i += 512) ((unsigned short*)dA)[i] = 0;
  if (tid < 384) {
    ((unsigned short*)xA)[3200 + tid] = 0;
    ((unsigned short*)y1A)[3200 + tid] = 0;
    ((unsigned short*)o1A)[3200 + tid] = 0;
  }
  for (int i = tid; i < 3200; i += 512) ((float*)s_deter)[i] = 0.f;
  if (tid < 160) {
    int r = tid / 10, k = tid % 10;
    sA[(30 + k) >> 3][r][(30 + k) & 7] = f2bf(action[((size_t)(b0 + r) * T_) * 10 + k]);
  }
  __syncthreads();

  for (int t = 0; t < T_; ++t) {
    // ---- stage1: x = elu([stoch|act] @ img1_w + img1_b) -> xA
    {
      s16x8 a0 = *(const s16x8*)&sA[kg][arow][0];
      s16x8 a1 = *(const s16x8*)&sA[4 + kg][arow][0];
#pragma unroll
      for (int i = 0; i < 2; ++i) {
        int nt = w + i * 8;
        const unsigned short* bp = pw1 + (nt * 2) * 512 + lane * 8;
        s16x8 b0v = *(const s16x8*)(bp);
        s16x8 b1v = *(const s16x8*)(bp + 512);
        int col = nt * 16 + arow;
        float bv = (col < 200) ? img1_b[col] : 0.f;
        f32x4 acc = {bv, bv, bv, bv};
        acc = __builtin_amdgcn_mfma_f32_16x16x32_bf16(a0, b0v, acc, 0, 0, 0);
        acc = __builtin_amdgcn_mfma_f32_16x16x32_bf16(a1, b1v, acc, 0, 0, 0);
        if (col < 200) {
#pragma unroll
          for (int rr = 0; rr < 4; ++rr)
            xA[col >> 3][kg * 4 + rr][col & 7] = f2bf(eluf(acc[rr]));
        }
      }
    }
    __syncthreads();

    // ---- stage2: gi = x@wi + bi ; gh = deter@wh + bh   (deter from t-1 via dA)
    {
      s16x8 ax[7], ad[7];
#pragma unroll
      for (int kt = 0; kt < 7; ++kt) {
        ax[kt] = *(const s16x8*)&xA[kt * 4 + kg][arow][0];
        ad[kt] = *(const s16x8*)&dA[kt * 4 + kg][arow][0];
      }
#pragma unroll
      for (int i = 0; i < 5; ++i) {
        int nt = w + i * 8;   // 0..39 (pads 38,39 guarded out)
        const unsigned short* bip = pwi + (nt * 7) * 512 + lane * 8;
        const unsigned short* bhp = pwh + (nt * 7) * 512 + lane * 8;
        s16x8 bi_[7], bh_[7];
#pragma unroll
        for (int kt = 0; kt < 7; ++kt) {
          bi_[kt] = *(const s16x8*)(bip + kt * 512);
          bh_[kt] = *(const s16x8*)(bhp + kt * 512);
        }
        int col = nt * 16 + arow;
        float bvi = (col < 600) ? gru_bi[col] : 0.f;
        float bvh = (col < 600) ? gru_bh[col] : 0.f;
        f32x4 ai = {bvi, bvi, bvi, bvi}, ah = {bvh, bvh, bvh, bvh};
#pragma unroll
        for (int kt = 0; kt < 7; ++kt) {
          ai = __builtin_amdgcn_mfma_f32_16x16x32_bf16(ax[kt], bi_[kt], ai, 0, 0, 0);
          ah = __builtin_amdgcn_mfma_f32_16x16x32_bf16(ad[kt], bh_[kt], ah, 0, 0, 0);
        }
        if (col < 600) {
          *(f32x4*)&s_gi[col][kg * 4] = ai;
          *(f32x4*)&s_gh[col][kg * 4] = ah;
        }
      }
    }
    __syncthreads();

    // ---- GRU elementwise -> s_deter (f32 carry) + dA (bf16 A-frags)
    {
#pragma unroll
      for (int u0 = 0; u0 < 2; ++u0) {
        int u = tid + u0 * 512;
        if (u < 800) {
          int c = u >> 2, rg = (u & 3) * 4;
          f32x4 ir = *(const f32x4*)&s_gi[c][rg];
          f32x4 iz = *(const f32x4*)&s_gi[c + 200][rg];
          f32x4 in_ = *(const f32x4*)&s_gi[c + 400][rg];
          f32x4 hr = *(const f32x4*)&s_gh[c][rg];
          f32x4 hz = *(const f32x4*)&s_gh[c + 200][rg];
          f32x4 hn = *(const f32x4*)&s_gh[c + 400][rg];
          f32x4 dv = *(const f32x4*)&s_deter[c][rg];
          f32x4 dn;
#pragma unroll
          for (int rr = 0; rr < 4; ++rr) {
            float r = sigmf(ir[rr] + hr[rr]);
            float z = sigmf(iz[rr] + hz[rr]);
            float n = tanh_(in_[rr] + r * hn[rr]);
            dn[rr] = (1.f - z) * n + z * dv[rr];
          }
          *(f32x4*)&s_deter[c][rg] = dn;
#pragma unroll
          for (int rr = 0; rr < 4; ++rr)
            dA[c >> 3][rg + rr][c & 7] = f2bf(dn[rr]);
        }
      }
    }
    __syncthreads();

    // ---- stage4: y1 = elu(deter@img2 + b2) ; o1 = elu(deter@obs1d + emb_pre)
    {
      s16x8 ad[7];
#pragma unroll
      for (int kt = 0; kt < 7; ++kt) ad[kt] = *(const s16x8*)&dA[kt * 4 + kg][arow][0];
#pragma unroll
      for (int i = 0; i < 4; ++i) {
        int u = w + i * 8;        // 0..31
        int mat = u >> 4;         // 0: img2 -> y1A ; 1: obs1d -> o1A
        int nt = u & 15;
        const unsigned short* bp = (mat ? po1 : pi2) + (nt * 7) * 512 + lane * 8;
        s16x8 bv[7];
#pragma unroll
        for (int kt = 0; kt < 7; ++kt) bv[kt] = *(const s16x8*)(bp + kt * 512);
        int col = nt * 16 + arow;
        float b0v = (!mat && col < 200) ? img2_b[col] : 0.f;
        f32x4 acc = {b0v, b0v, b0v, b0v};
#pragma unroll
        for (int kt = 0; kt < 7; ++kt)
          acc = __builtin_amdgcn_mfma_f32_16x16x32_bf16(ad[kt], bv[kt], acc, 0, 0, 0);
        if (col < 200) {
          if (mat) {
            size_t eb = ((size_t)t * 1024 + b0) * 200 + col;
#pragma unroll
            for (int rr = 0; rr < 4; ++rr) {
              float e = bf2f(emb_pre[eb + (size_t)(kg * 4 + rr) * 200]);
              o1A[col >> 3][kg * 4 + rr][col & 7] = f2bf(eluf(acc[rr] + e));
            }
          } else {
#pragma unroll
            for (int rr = 0; rr < 4; ++rr)
              y1A[col >> 3][kg * 4 + rr][col & 7] = f2bf(eluf(acc[rr]));
          }
        }
      }
    }
    __syncthreads();

    // ---- stage5: y = y1@img3 + b3 ; o = o1@obs2 + bo
    {
      int mat = w >> 2, nt = w & 3;
      const unsigned short* asrc = mat ? &o1A[0][0][0] : &y1A[0][0][0];
      s16x8 av[7];
#pragma unroll
      for (int kt = 0; kt < 7; ++kt)
        av[kt] = *(const s16x8*)(asrc + ((kt * 4 + kg) * 16 + arow) * 8);
      const unsigned short* bp = (mat ? po2 : pi3) + (nt * 7) * 512 + lane * 8;
      int col = nt * 16 + arow;
      float bv = (col < 60) ? (mat ? obs2_b[col] : img3_b[col]) : 0.f;
      f32x4 acc = {bv, bv, bv, bv};
#pragma unroll
      for (int kt = 0; kt < 7; ++kt) {
        s16x8 bb = *(const s16x8*)(bp + kt * 512);
        acc = __builtin_amdgcn_mfma_f32_16x16x32_bf16(av[kt], bb, acc, 0, 0, 0);
      }
      if (col < 60) {
        if (mat) *(f32x4*)&s_o[col][kg * 4] = acc;
        else     *(f32x4*)&s_y[col][kg * 4] = acc;
      }
    }
    __syncthreads();

    // ---- sampling + outputs + next-step action load
    {
      if (tid < 480) {
        int r = tid / 30, j = tid % 30;
        size_t ob = ((size_t)(b0 + r) * T_ + t) * 580;
        size_t eo = ((size_t)t * 1024 + (b0 + r)) * 30 + j;
        float qm = s_o[j][r];
        float qs = softpf(s_o[j + 30][r]) + 0.1f;
        float qst = qm + qs * eps_post[eo];
        out[ob + j] = qm; out[ob + 30 + j] = qs; out[ob + 60 + j] = qst;
        sA[j >> 3][r][j & 7] = f2bf(qst);
        float pm = s_y[j][r];
        float ps = softpf(s_y[j + 30][r]) + 0.1f;
        float pst = pm + ps * eps_prior[eo];
        out[ob + 290 + j] = pm; out[ob + 320 + j] = ps; out[ob + 350 + j] = pst;
      }
      if (t + 1 < T_ && tid < 160) {
        int r = tid / 10, k = tid % 10;
        sA[(30 + k) >> 3][r][(30 + k) & 7] =
            f2bf(action[((size_t)(b0 + r) * T_ + (t + 1)) * 10 + k]);
      }
      for (int idx = tid; idx < 3200; idx += 512) {
        int n = idx % 200, r = idx / 200;
        float v = s_deter[n][r];
        size_t ob = ((size_t)(b0 + r) * T_ + t) * 580;
        out[ob + 90 + n] = v;
        out[ob + 380 + n] = v;
      }
    }
    __syncthreads();
  }
}

extern "C" void kernel_launch(void* const* d_in, const int* in_sizes, int n_in,
                              void* d_out, int out_size, void* d_ws, size_t ws_size,
                              hipStream_t stream) {
  const float* embed    = (const float*)d_in[0];
  const float* action   = (const float*)d_in[1];
  const float* eps_post = (const float*)d_in[2];
  const float* eps_prior= (const float*)d_in[3];
  const float* img1_w   = (const float*)d_in[4];
  const float* img1_b   = (const float*)d_in[5];
  const float* gru_wi   = (const float*)d_in[6];
  const float* gru_wh   = (const float*)d_in[7];
  const float* gru_bi   = (const float*)d_in[8];
  const float* gru_bh   = (const float*)d_in[9];
  const float* img2_w   = (const float*)d_in[10];
  const float* img2_b   = (const float*)d_in[11];
  const float* img3_w   = (const float*)d_in[12];
  const float* img3_b   = (const float*)d_in[13];
  const float* obs1_w   = (const float*)d_in[14];
  const float* obs1_b   = (const float*)d_in[15];
  const float* obs2_w   = (const float*)d_in[16];
  const float* obs2_b   = (const float*)d_in[17];

  char* ws = (char*)d_ws;
  unsigned short* emb_pre = (unsigned short*)ws;
  unsigned short* pkw     = (unsigned short*)(ws + OFF_PK);
  unsigned short* swz     = (unsigned short*)(ws + OFF_SWZ);
  float* outp = (float*)d_out;

  prep_weights<<<256, 256, 0, stream>>>(img1_w, gru_wi, gru_wh, img2_w, img3_w,
                                        obs1_w, obs2_w, pkw, swz);
  emb_gemm<<<1024, 256, 0, stream>>>(embed, obs1_b, swz, emb_pre);
  scan16<<<64, 512, 0, stream>>>(action, eps_post, eps_prior, img1_b, gru_bi,
                                 gru_bh, img2_b, img3_b, obs2_b, pkw,
                                 emb_pre, outp);
}

// Round 3
// 2303.329 us; speedup vs baseline: 1.0992x; 1.0992x over previous
//
#include <hip/hip_runtime.h>

#define T_ 64

typedef __attribute__((ext_vector_type(4))) float f32x4;
typedef __attribute__((ext_vector_type(8))) short s16x8;

__device__ __forceinline__ unsigned short f2bf(float f) {
  unsigned u = __float_as_uint(f);
  u = (u + 0x7FFFu + ((u >> 16) & 1u)) >> 16;
  return (unsigned short)u;
}
__device__ __forceinline__ float bf2f(unsigned short h) {
  return __uint_as_float(((unsigned)h) << 16);
}
__device__ __forceinline__ float eluf(float x) { return x > 0.f ? x : __expf(x) - 1.f; }
__device__ __forceinline__ float sigmf(float x) { return 1.f / (1.f + __expf(-x)); }
__device__ __forceinline__ float tanh_(float x) {
  float xx = fminf(fmaxf(x, -30.f), 30.f);
  float e = __expf(-2.f * xx);
  return (1.f - e) / (1.f + e);
}
__device__ __forceinline__ float softpf(float x) {
  return x > 20.f ? x : __logf(1.f + __expf(x));
}

// ---- workspace layout ----
// emb_pre (bf16) [T*B][200] : 26,214,400 B
// pk (bf16 packed weights)  :    835,584 B
// swz (emb_gemm B)          :    425,984 B
#define OFF_PK  26214400
#define OFF_SWZ 27049984

// pk layout (u16 offsets):
//  pw1 @0       KT2 NT16     (16384)
//  pwi @16384   gru perm 39*7*512 = 139776
//  pwh @156160  gru perm 139776
//  pi2 @295936  KT7 NT13 (46592)
//  po1 @342528  KT7 NT13 (46592)
//  pi3 @389120  KT7 NT4  (14336)
//  po2 @403456  KT7 NT4  (14336)

// Packed B layout: idx = ((nt*KT + kt)*64 + lane)*8 + j ; W[k][n],
// n = nt*16 + (lane&15), k = kt*32 + (lane>>4)*8 + j; zero-padded.
__device__ void pack_mat(int idx, int stride, const float* __restrict__ W,
                         int K, int N, int KT, int NT, unsigned short* __restrict__ dst) {
  int total = KT * NT * 512;
  for (int i = idx; i < total; i += stride) {
    int j = i & 7, l = (i >> 3) & 63, rem = i >> 9;
    int kt = rem % KT, nt = rem / KT;
    int n = nt * 16 + (l & 15), k = kt * 32 + (l >> 4) * 8 + j;
    float v = (k < K && n < N) ? W[(size_t)k * N + n] : 0.f;
    dst[i] = f2bf(v);
  }
}

// GRU weights, gate-padded permutation: packed col c = g*208 + u
// (g=gate 0..2 = r,z,n ; u = hidden unit). 39 tiles of 16 cols, KT=7.
__device__ void pack_gru(int idx, int stride, const float* __restrict__ W,
                         unsigned short* __restrict__ dst) {
  int total = 39 * 7 * 512;
  for (int i = idx; i < total; i += stride) {
    int j = i & 7, l = (i >> 3) & 63, rem = i >> 9;
    int kt = rem % 7, nt = rem / 7;
    int c = nt * 16 + (l & 15);
    int g = c / 208, u = c - g * 208;
    int k = kt * 32 + (l >> 4) * 8 + j;
    float v = (u < 200 && k < 200) ? W[(size_t)k * 600 + g * 200 + u] : 0.f;
    dst[i] = f2bf(v);
  }
}

__global__ void prep_weights(const float* __restrict__ w1, const float* __restrict__ wi,
                             const float* __restrict__ wh, const float* __restrict__ i2,
                             const float* __restrict__ i3, const float* __restrict__ obs1w,
                             const float* __restrict__ o2,
                             unsigned short* __restrict__ pk,
                             unsigned short* __restrict__ swz) {
  int idx = blockIdx.x * blockDim.x + threadIdx.x;
  int stride = gridDim.x * blockDim.x;
  pack_mat(idx, stride, w1, 40, 200, 2, 16, pk);
  pack_gru(idx, stride, wi, pk + 16384);
  pack_gru(idx, stride, wh, pk + 156160);
  pack_mat(idx, stride, i2, 200, 200, 7, 13, pk + 295936);
  pack_mat(idx, stride, obs1w, 200, 200, 7, 13, pk + 342528);
  pack_mat(idx, stride, i3, 200, 60, 7, 4, pk + 389120);
  pack_mat(idx, stride, o2, 200, 60, 7, 4, pk + 403456);
  // swz for emb_gemm (validated layout)
  for (int i = idx; i < 212992; i += stride) {
    int j = i & 7, l = (i >> 3) & 63, rem = i >> 9;
    int nt = rem % 13, kc = rem / 13;
    int k = kc * 32 + ((l >> 4) * 8) + j;
    int n = nt * 16 + (l & 15);
    float v = (n < 200) ? obs1w[(size_t)(200 + k) * 200 + n] : 0.0f;
    swz[i] = f2bf(v);
  }
}

// --------------------------------------------------------------------------
// emb_pre = embed @ obs1_w[200:,:] + obs1_b   (validated round-1 kernel)
// --------------------------------------------------------------------------
__global__ __launch_bounds__(256) void emb_gemm(const float* __restrict__ embed,
                                                const float* __restrict__ obs1b,
                                                const unsigned short* __restrict__ swz,
                                                unsigned short* __restrict__ emb_pre) {
  __shared__ __align__(16) unsigned short lds_A[64][40];
  int tid = threadIdx.x;
  int lane = tid & 63, w = tid >> 6;
  int R0 = blockIdx.x * 64;
  int tt = R0 >> 10;
  int bb = R0 & 1023;

  f32x4 acc[13];
#pragma unroll
  for (int nt = 0; nt < 13; ++nt) acc[nt] = (f32x4){0.f, 0.f, 0.f, 0.f};

  int i_row = tid >> 2, cg = tid & 3;
  const float* arow = embed + ((size_t)(bb + i_row) * 64 + tt) * 1024 + cg * 8;

  for (int kc = 0; kc < 32; ++kc) {
    __syncthreads();
    {
      const float* p = arow + kc * 32;
      f32x4 a0 = *(const f32x4*)p;
      f32x4 a1 = *(const f32x4*)(p + 4);
      unsigned short* dst = &lds_A[i_row][cg * 8];
      dst[0] = f2bf(a0[0]); dst[1] = f2bf(a0[1]); dst[2] = f2bf(a0[2]); dst[3] = f2bf(a0[3]);
      dst[4] = f2bf(a1[0]); dst[5] = f2bf(a1[1]); dst[6] = f2bf(a1[2]); dst[7] = f2bf(a1[3]);
    }
    __syncthreads();
    s16x8 af = *(const s16x8*)&lds_A[w * 16 + (lane & 15)][(lane >> 4) * 8];
    const unsigned short* bp = swz + (size_t)kc * 6656 + (size_t)lane * 8;
#pragma unroll
    for (int nt = 0; nt < 13; ++nt) {
      s16x8 bfv = *(const s16x8*)(bp + nt * 512);
      acc[nt] = __builtin_amdgcn_mfma_f32_16x16x32_bf16(af, bfv, acc[nt], 0, 0, 0);
    }
  }
  int r0 = R0 + w * 16 + ((lane >> 4) << 2);
  int c0 = lane & 15;
#pragma unroll
  for (int nt = 0; nt < 13; ++nt) {
    int n = nt * 16 + c0;
    if (n < 200) {
      float bv = obs1b[n];
#pragma unroll
      for (int rr = 0; rr < 4; ++rr)
        emb_pre[(size_t)(r0 + rr) * 200 + n] = f2bf(acc[nt][rr] + bv);
    }
  }
}

// --------------------------------------------------------------------------
// Streaming MFMA scan: 64 blocks x 512 thr. Per-wave LDS ring (14 x 1KB),
// global_load_lds + counted vmcnt, raw barriers, GRU fused in registers.
// --------------------------------------------------------------------------
#define WAITV7 asm volatile("s_waitcnt vmcnt(7)" ::: "memory")
#define WAITV0 asm volatile("s_waitcnt vmcnt(0)" ::: "memory")
#define LGKM0  asm volatile("s_waitcnt lgkmcnt(0)" ::: "memory")
#define MEMCLB asm volatile("" ::: "memory")
#define BAR()  __builtin_amdgcn_s_barrier()

typedef __attribute__((address_space(3))) unsigned int u32_lds;
typedef const __attribute__((address_space(1))) unsigned int u32_glb;

__device__ __forceinline__ void gll16(const unsigned short* g, unsigned short* l, int lane) {
  __builtin_amdgcn_global_load_lds((u32_glb*)(g + lane * 8), (u32_lds*)l, 16, 0, 0);
}

__device__ __forceinline__ void issue7(const unsigned short* gbase,
                                       unsigned short (*ringw)[512], int base, int lane) {
#pragma unroll
  for (int i = 0; i < 7; ++i) {
    int s = base + i; if (s >= 14) s -= 14;
    gll16(gbase + i * 512, &ringw[s][0], lane);
  }
}

template <int LAST>
__device__ __forceinline__ void chunk_mfma(const unsigned short (*ringw)[512], int lane,
                                           int base, const s16x8* A, f32x4& acc) {
  if (LAST) { WAITV0; } else { WAITV7; }
  s16x8 Bv[7];
#pragma unroll
  for (int i = 0; i < 7; ++i) {
    int s = base + i; if (s >= 14) s -= 14;
    Bv[i] = *(const s16x8*)&ringw[s][lane * 8];
  }
#pragma unroll
  for (int i = 0; i < 7; ++i)
    acc = __builtin_amdgcn_mfma_f32_16x16x32_bf16(A[i], Bv[i], acc, 0, 0, 0);
  MEMCLB;
}

__device__ __forceinline__ void read_afrags(const unsigned short* src, int kg, int arow, s16x8* A) {
#pragma unroll
  for (int kt = 0; kt < 7; ++kt)
    A[kt] = *(const s16x8*)(src + (size_t)((kt * 4 + kg) * 16 + arow) * 8);
}

__device__ __forceinline__ void gru_step(const f32x4& ir, const f32x4& hr, const f32x4& iz,
                                         const f32x4& hz, const f32x4& in_, const f32x4& hn,
                                         f32x4& dv) {
#pragma unroll
  for (int rr = 0; rr < 4; ++rr) {
    float r = sigmf(ir[rr] + hr[rr]);
    float z = sigmf(iz[rr] + hz[rr]);
    float n = tanh_(in_[rr] + r * hn[rr]);
    dv[rr] = (1.f - z) * n + z * dv[rr];
  }
}

__global__ __launch_bounds__(512, 2) void scan_stream(
    const float* __restrict__ action, const float* __restrict__ eps_post,
    const float* __restrict__ eps_prior, const float* __restrict__ img1_b,
    const float* __restrict__ gru_bi, const float* __restrict__ gru_bh,
    const float* __restrict__ img2_b, const float* __restrict__ img3_b,
    const float* __restrict__ obs2_b, const unsigned short* __restrict__ pk,
    const unsigned short* __restrict__ emb_pre, float* __restrict__ out) {

  __shared__ __align__(16) unsigned short ring[8][14][512];   // 112 KB
  __shared__ __align__(16) unsigned short xA[28][16][8];
  __shared__ __align__(16) unsigned short dA[28][16][8];
  __shared__ __align__(16) unsigned short y1A[28][16][8];
  __shared__ __align__(16) unsigned short o1A[28][16][8];
  __shared__ __align__(16) unsigned short sA[8][16][8];
  __shared__ __align__(16) float s_y[60][20];
  __shared__ __align__(16) float s_o[60][20];

  const unsigned short* pw1 = pk;
  const unsigned short* pwi = pk + 16384;
  const unsigned short* pwh = pk + 156160;
  const unsigned short* pi2 = pk + 295936;
  const unsigned short* po1 = pk + 342528;
  const unsigned short* pi3 = pk + 389120;
  const unsigned short* po2 = pk + 403456;

  const int tid = threadIdx.x;
  const int lane = tid & 63;
  const int w = tid >> 6;
  const int arow = lane & 15;
  const int kg = lane >> 4;
  const int b0 = blockIdx.x * 16;
  unsigned short (*ringw)[512] = ring[w];

  const int colA = w * 16 + arow;                       // < 128
  const int colB = (w + 8) * 16 + arow;                 // 128..255
  const int colBc = colB < 200 ? colB : 199;
  const int col5 = (w & 3) * 16 + arow;

  // ---- prologue ----
  {
    unsigned short* xf = &xA[0][0][0];
    unsigned short* df = &dA[0][0][0];
    unsigned short* yf = &y1A[0][0][0];
    unsigned short* of = &o1A[0][0][0];
    for (int i = tid; i < 3584; i += 512) { xf[i] = 0; df[i] = 0; yf[i] = 0; of[i] = 0; }
    unsigned short* sf = &sA[0][0][0];
    for (int i = tid; i < 1024; i += 512) sf[i] = 0;
  }
  __syncthreads();
  if (tid < 160) {
    int r = tid / 10, k = tid % 10;
    sA[(30 + k) >> 3][r][(30 + k) & 7] = f2bf(action[((size_t)(b0 + r) * T_) * 10 + k]);
  }
  // biases (registers)
  float b1a = img1_b[colA];
  float b1b = (w < 5) ? img1_b[colBc] : 0.f;
  float bi1_0 = gru_bi[colA], bi1_1 = gru_bi[200 + colA], bi1_2 = gru_bi[400 + colA];
  float bh1_0 = gru_bh[colA], bh1_1 = gru_bh[200 + colA], bh1_2 = gru_bh[400 + colA];
  float bi2_0 = 0, bi2_1 = 0, bi2_2 = 0, bh2_0 = 0, bh2_1 = 0, bh2_2 = 0;
  if (w < 5) {
    bi2_0 = gru_bi[colBc]; bi2_1 = gru_bi[200 + colBc]; bi2_2 = gru_bi[400 + colBc];
    bh2_0 = gru_bh[colBc]; bh2_1 = gru_bh[200 + colBc]; bh2_2 = gru_bh[400 + colBc];
  }
  float b4a = img2_b[colA];
  float b4b = (w < 5) ? img2_b[colBc] : 0.f;
  float b5 = (col5 < 60) ? ((w >= 4) ? obs2_b[col5] : img3_b[col5]) : 0.f;
  // persistent stage5 B fragments
  s16x8 wB5[7];
  {
    const unsigned short* p5 = ((w >= 4) ? po2 : pi3) + (size_t)((w & 3) * 7) * 512 + lane * 8;
#pragma unroll
    for (int kt = 0; kt < 7; ++kt) wB5[kt] = *(const s16x8*)(p5 + kt * 512);
  }
  // emb prefetch for t=0
  unsigned short e[8];
  {
    size_t eb = (size_t)b0 * 200;
#pragma unroll
    for (int rr = 0; rr < 4; ++rr) {
      e[rr] = emb_pre[eb + (size_t)(kg * 4 + rr) * 200 + colA];
      e[4 + rr] = (w < 5) ? emb_pre[eb + (size_t)(kg * 4 + rr) * 200 + colBc] : (unsigned short)0;
    }
  }
  f32x4 dv0 = {0.f, 0.f, 0.f, 0.f}, dv1 = {0.f, 0.f, 0.f, 0.f};
  // issue C0 (s1) + C1 (wi gate r)
  {
    gll16(pw1 + (w * 2 + 0) * 512, &ringw[0][0], lane);
    gll16(pw1 + (w * 2 + 1) * 512, &ringw[1][0], lane);
    if (w < 5) {
      gll16(pw1 + ((w + 8) * 2 + 0) * 512, &ringw[2][0], lane);
      gll16(pw1 + ((w + 8) * 2 + 1) * 512, &ringw[3][0], lane);
      issue7(pwi + (size_t)(w * 7) * 512, ringw, 4, lane);
    } else {
      issue7(pwi + (size_t)(w * 7) * 512, ringw, 2, lane);
    }
  }
  __syncthreads();

  for (int t = 0; t < T_; ++t) {
    // ---------- ITER 0: stage1 ----------
    WAITV7;
    {
      s16x8 a0 = *(const s16x8*)&sA[kg][arow][0];
      s16x8 a1 = *(const s16x8*)&sA[4 + kg][arow][0];
      s16x8 B0 = *(const s16x8*)&ringw[0][lane * 8];
      s16x8 B1 = *(const s16x8*)&ringw[1][lane * 8];
      f32x4 acc0 = {b1a, b1a, b1a, b1a};
      acc0 = __builtin_amdgcn_mfma_f32_16x16x32_bf16(a0, B0, acc0, 0, 0, 0);
      acc0 = __builtin_amdgcn_mfma_f32_16x16x32_bf16(a1, B1, acc0, 0, 0, 0);
#pragma unroll
      for (int rr = 0; rr < 4; ++rr)
        xA[colA >> 3][kg * 4 + rr][colA & 7] = f2bf(eluf(acc0[rr]));
      if (w < 5) {
        s16x8 B2 = *(const s16x8*)&ringw[2][lane * 8];
        s16x8 B3 = *(const s16x8*)&ringw[3][lane * 8];
        f32x4 acc1 = {b1b, b1b, b1b, b1b};
        acc1 = __builtin_amdgcn_mfma_f32_16x16x32_bf16(a0, B2, acc1, 0, 0, 0);
        acc1 = __builtin_amdgcn_mfma_f32_16x16x32_bf16(a1, B3, acc1, 0, 0, 0);
        if (colB < 200) {
#pragma unroll
          for (int rr = 0; rr < 4; ++rr)
            xA[colB >> 3][kg * 4 + rr][colB & 7] = f2bf(eluf(acc1[rr]));
        }
      }
    }
    MEMCLB;
    if (w < 5) issue7(pwh + (size_t)(w * 7) * 512, ringw, 11, lane);
    else       issue7(pwh + (size_t)(w * 7) * 512, ringw, 9, lane);
    LGKM0; BAR();                       // B1: xA ready

    // ---------- stage2 + fused GRU ----------
    {
      s16x8 ax[7], ad[7];
      read_afrags(&xA[0][0][0], kg, arow, ax);
      read_afrags(&dA[0][0][0], kg, arow, ad);
      if (w < 5) {
        f32x4 ai0 = {bi1_0, bi1_0, bi1_0, bi1_0};
        chunk_mfma<0>(ringw, lane, 4, ax, ai0);
        issue7(pwi + (size_t)((13 + w) * 7) * 512, ringw, 4, lane);
        f32x4 ah0 = {bh1_0, bh1_0, bh1_0, bh1_0};
        chunk_mfma<0>(ringw, lane, 11, ad, ah0);
        issue7(pwh + (size_t)((13 + w) * 7) * 512, ringw, 11, lane);
        f32x4 ai1 = {bi1_1, bi1_1, bi1_1, bi1_1};
        chunk_mfma<0>(ringw, lane, 4, ax, ai1);
        issue7(pwi + (size_t)((26 + w) * 7) * 512, ringw, 4, lane);
        f32x4 ah1 = {bh1_1, bh1_1, bh1_1, bh1_1};
        chunk_mfma<0>(ringw, lane, 11, ad, ah1);
        issue7(pwh + (size_t)((26 + w) * 7) * 512, ringw, 11, lane);
        f32x4 ai2 = {bi1_2, bi1_2, bi1_2, bi1_2};
        chunk_mfma<0>(ringw, lane, 4, ax, ai2);
        issue7(pwi + (size_t)((w + 8) * 7) * 512, ringw, 4, lane);
        f32x4 ah2 = {bh1_2, bh1_2, bh1_2, bh1_2};
        chunk_mfma<0>(ringw, lane, 11, ad, ah2);
        issue7(pwh + (size_t)((w + 8) * 7) * 512, ringw, 11, lane);
        gru_step(ai0, ah0, ai1, ah1, ai2, ah2, dv0);
        // triple 2 (tau = w+8)
        f32x4 bi0v = {bi2_0, bi2_0, bi2_0, bi2_0};
        chunk_mfma<0>(ringw, lane, 4, ax, bi0v);
        issue7(pwi + (size_t)((13 + w + 8) * 7) * 512, ringw, 4, lane);
        f32x4 bh0v = {bh2_0, bh2_0, bh2_0, bh2_0};
        chunk_mfma<0>(ringw, lane, 11, ad, bh0v);
        issue7(pwh + (size_t)((13 + w + 8) * 7) * 512, ringw, 11, lane);
        f32x4 bi1v = {bi2_1, bi2_1, bi2_1, bi2_1};
        chunk_mfma<0>(ringw, lane, 4, ax, bi1v);
        issue7(pwi + (size_t)((26 + w + 8) * 7) * 512, ringw, 4, lane);
        f32x4 bh1v = {bh2_1, bh2_1, bh2_1, bh2_1};
        chunk_mfma<0>(ringw, lane, 11, ad, bh1v);
        issue7(pwh + (size_t)((26 + w + 8) * 7) * 512, ringw, 11, lane);
        f32x4 bi2v = {bi2_2, bi2_2, bi2_2, bi2_2};
        chunk_mfma<0>(ringw, lane, 4, ax, bi2v);
        issue7(pi2 + (size_t)(w * 7) * 512, ringw, 4, lane);
        f32x4 bh2v = {bh2_2, bh2_2, bh2_2, bh2_2};
        chunk_mfma<0>(ringw, lane, 11, ad, bh2v);
        issue7(pi2 + (size_t)((w + 8) * 7) * 512, ringw, 11, lane);
        gru_step(bi0v, bh0v, bi1v, bh1v, bi2v, bh2v, dv1);
      } else {
        f32x4 ai0 = {bi1_0, bi1_0, bi1_0, bi1_0};
        chunk_mfma<0>(ringw, lane, 2, ax, ai0);
        issue7(pwi + (size_t)((13 + w) * 7) * 512, ringw, 2, lane);
        f32x4 ah0 = {bh1_0, bh1_0, bh1_0, bh1_0};
        chunk_mfma<0>(ringw, lane, 9, ad, ah0);
        issue7(pwh + (size_t)((13 + w) * 7) * 512, ringw, 9, lane);
        f32x4 ai1 = {bi1_1, bi1_1, bi1_1, bi1_1};
        chunk_mfma<0>(ringw, lane, 2, ax, ai1);
        issue7(pwi + (size_t)((26 + w) * 7) * 512, ringw, 2, lane);
        f32x4 ah1 = {bh1_1, bh1_1, bh1_1, bh1_1};
        chunk_mfma<0>(ringw, lane, 9, ad, ah1);
        issue7(pwh + (size_t)((26 + w) * 7) * 512, ringw, 9, lane);
        f32x4 ai2 = {bi1_2, bi1_2, bi1_2, bi1_2};
        chunk_mfma<0>(ringw, lane, 2, ax, ai2);
        issue7(pi2 + (size_t)(w * 7) * 512, ringw, 2, lane);
        f32x4 ah2 = {bh1_2, bh1_2, bh1_2, bh1_2};
        chunk_mfma<0>(ringw, lane, 9, ad, ah2);
        issue7(po1 + (size_t)(w * 7) * 512, ringw, 9, lane);
        gru_step(ai0, ah0, ai1, ah1, ai2, ah2, dv0);
      }
    }
    LGKM0; BAR();                       // B2: stage2 reads of dA done
    // deter -> dA (bf16 A-frags)
    {
#pragma unroll
      for (int rr = 0; rr < 4; ++rr)
        dA[colA >> 3][kg * 4 + rr][colA & 7] = f2bf(dv0[rr]);
      if (w < 5 && colB < 200) {
#pragma unroll
        for (int rr = 0; rr < 4; ++rr)
          dA[colB >> 3][kg * 4 + rr][colB & 7] = f2bf(dv1[rr]);
      }
    }
    LGKM0; BAR();                       // B2b: dA ready

    // ---------- stage4 ----------
    {
      s16x8 ad4[7];
      read_afrags(&dA[0][0][0], kg, arow, ad4);
      if (w < 5) {
        f32x4 c0 = {b4a, b4a, b4a, b4a};
        chunk_mfma<0>(ringw, lane, 4, ad4, c0);
        issue7(po1 + (size_t)(w * 7) * 512, ringw, 4, lane);
#pragma unroll
        for (int rr = 0; rr < 4; ++rr)
          y1A[colA >> 3][kg * 4 + rr][colA & 7] = f2bf(eluf(c0[rr]));
        f32x4 c1 = {b4b, b4b, b4b, b4b};
        chunk_mfma<0>(ringw, lane, 11, ad4, c1);
        issue7(po1 + (size_t)((w + 8) * 7) * 512, ringw, 11, lane);
        if (colB < 200) {
#pragma unroll
          for (int rr = 0; rr < 4; ++rr)
            y1A[colB >> 3][kg * 4 + rr][colB & 7] = f2bf(eluf(c1[rr]));
        }
        f32x4 c2 = {0.f, 0.f, 0.f, 0.f};
        chunk_mfma<0>(ringw, lane, 4, ad4, c2);
#pragma unroll
        for (int rr = 0; rr < 4; ++rr)
          o1A[colA >> 3][kg * 4 + rr][colA & 7] = f2bf(eluf(c2[rr] + bf2f(e[rr])));
        f32x4 c3 = {0.f, 0.f, 0.f, 0.f};
        chunk_mfma<1>(ringw, lane, 11, ad4, c3);
        if (colB < 200) {
#pragma unroll
          for (int rr = 0; rr < 4; ++rr)
            o1A[colB >> 3][kg * 4 + rr][colB & 7] = f2bf(eluf(c3[rr] + bf2f(e[4 + rr])));
        }
      } else {
        f32x4 c0 = {b4a, b4a, b4a, b4a};
        chunk_mfma<0>(ringw, lane, 2, ad4, c0);
#pragma unroll
        for (int rr = 0; rr < 4; ++rr)
          y1A[colA >> 3][kg * 4 + rr][colA & 7] = f2bf(eluf(c0[rr]));
        f32x4 c2 = {0.f, 0.f, 0.f, 0.f};
        chunk_mfma<1>(ringw, lane, 9, ad4, c2);
#pragma unroll
        for (int rr = 0; rr < 4; ++rr)
          o1A[colA >> 3][kg * 4 + rr][colA & 7] = f2bf(eluf(c2[rr] + bf2f(e[rr])));
      }
    }
    LGKM0; BAR();                       // B3: y1A/o1A ready

    // ---------- stage5 (persistent B) ----------
    {
      s16x8 a5[7];
      read_afrags((w >= 4) ? &o1A[0][0][0] : &y1A[0][0][0], kg, arow, a5);
      f32x4 c5 = {b5, b5, b5, b5};
#pragma unroll
      for (int kt = 0; kt < 7; ++kt)
        c5 = __builtin_amdgcn_mfma_f32_16x16x32_bf16(a5[kt], wB5[kt], c5, 0, 0, 0);
      if (col5 < 60) {
        if (w >= 4) *(f32x4*)&s_o[col5][kg * 4] = c5;
        else        *(f32x4*)&s_y[col5][kg * 4] = c5;
      }
    }
    LGKM0; BAR();                       // B4: s_y/s_o ready

    // ---------- sampling / outputs / next-step staging ----------
    {
      // deter outputs (f32 carry in regs)
#pragma unroll
      for (int rr = 0; rr < 4; ++rr) {
        size_t ob = ((size_t)(b0 + kg * 4 + rr) * T_ + t) * 580;
        out[ob + 90 + colA] = dv0[rr];
        out[ob + 380 + colA] = dv0[rr];
        if (w < 5 && colB < 200) {
          out[ob + 90 + colB] = dv1[rr];
          out[ob + 380 + colB] = dv1[rr];
        }
      }
      if (tid < 480) {
        int r = tid / 30, j = tid % 30;
        size_t ob = ((size_t)(b0 + r) * T_ + t) * 580;
        size_t eo = ((size_t)t * 1024 + (b0 + r)) * 30 + j;
        float qm = s_o[j][r];
        float qs = softpf(s_o[j + 30][r]) + 0.1f;
        float qst = qm + qs * eps_post[eo];
        out[ob + j] = qm; out[ob + 30 + j] = qs; out[ob + 60 + j] = qst;
        sA[j >> 3][r][j & 7] = f2bf(qst);
        float pm = s_y[j][r];
        float ps = softpf(s_y[j + 30][r]) + 0.1f;
        float pst = pm + ps * eps_prior[eo];
        out[ob + 290 + j] = pm; out[ob + 320 + j] = ps; out[ob + 350 + j] = pst;
      }
      if (t + 1 < T_) {
        if (tid < 160) {
          int r = tid / 10, k = tid % 10;
          sA[(30 + k) >> 3][r][(30 + k) & 7] =
              f2bf(action[((size_t)(b0 + r) * T_ + (t + 1)) * 10 + k]);
        }
        // emb prefetch for t+1
        size_t eb = ((size_t)(t + 1) * 1024 + b0) * 200;
#pragma unroll
        for (int rr = 0; rr < 4; ++rr) {
          e[rr] = emb_pre[eb + (size_t)(kg * 4 + rr) * 200 + colA];
          e[4 + rr] = (w < 5) ? emb_pre[eb + (size_t)(kg * 4 + rr) * 200 + colBc]
                              : (unsigned short)0;
        }
        MEMCLB;
        // issue next step's C0 (s1) + C1 (wi gate r)
        gll16(pw1 + (w * 2 + 0) * 512, &ringw[0][0], lane);
        gll16(pw1 + (w * 2 + 1) * 512, &ringw[1][0], lane);
        if (w < 5) {
          gll16(pw1 + ((w + 8) * 2 + 0) * 512, &ringw[2][0], lane);
          gll16(pw1 + ((w + 8) * 2 + 1) * 512, &ringw[3][0], lane);
          issue7(pwi + (size_t)(w * 7) * 512, ringw, 4, lane);
        } else {
          issue7(pwi + (size_t)(w * 7) * 512, ringw, 2, lane);
        }
      }
    }
    LGKM0; BAR();                       // B5: sA ready for next step
  }
}

extern "C" void kernel_launch(void* const* d_in, const int* in_sizes, int n_in,
                              void* d_out, int out_size, void* d_ws, size_t ws_size,
                              hipStream_t stream) {
  const float* embed    = (const float*)d_in[0];
  const float* action   = (const float*)d_in[1];
  const float* eps_post = (const float*)d_in[2];
  const float* eps_prior= (const float*)d_in[3];
  const float* img1_w   = (const float*)d_in[4];
  const float* img1_b   = (const float*)d_in[5];
  const float* gru_wi   = (const float*)d_in[6];
  const float* gru_wh   = (const float*)d_in[7];
  const float* gru_bi   = (const float*)d_in[8];
  const float* gru_bh   = (const float*)d_in[9];
  const float* img2_w   = (const float*)d_in[10];
  const float* img2_b   = (const float*)d_in[11];
  const float* img3_w   = (const float*)d_in[12];
  const float* img3_b   = (const float*)d_in[13];
  const float* obs1_w   = (const float*)d_in[14];
  const float* obs1_b   = (const float*)d_in[15];
  const float* obs2_w   = (const float*)d_in[16];
  const float* obs2_b   = (const float*)d_in[17];

  char* ws = (char*)d_ws;
  unsigned short* emb_pre = (unsigned short*)ws;
  unsigned short* pkw     = (unsigned short*)(ws + OFF_PK);
  unsigned short* swz     = (unsigned short*)(ws + OFF_SWZ);
  float* outp = (float*)d_out;

  prep_weights<<<256, 256, 0, stream>>>(img1_w, gru_wi, gru_wh, img2_w, img3_w,
                                        obs1_w, obs2_w, pkw, swz);
  emb_gemm<<<1024, 256, 0, stream>>>(embed, obs1_b, swz, emb_pre);
  scan_stream<<<64, 512, 0, stream>>>(action, eps_post, eps_prior, img1_b, gru_bi,
                                      gru_bh, img2_b, img3_b, obs2_b, pkw,
                                      emb_pre, outp);
}